// Round 13
// baseline (503.799 us; speedup 1.0000x reference)
//
#include <hip/hip_runtime.h>
#include <hip/hip_bf16.h>

// VS_DiT_Block: AdaLN-modulated DiT block (self-attn + cross-attn + MLP)
// B=4, N=1024, D=1024, H=16, HD=64, S=77, MLP=4096. f32 I/O, fp16 MFMA compute,
// f32 residual chain. Weights pre-transposed to f16 W^T[N][K] once per launch.

#define D_MODEL 1024
#define NHEAD   16
#define HDIM    64
#define SEQ_N   1024
#define SEQ_S   77
#define BATCH   4
#define MLP_DIM 4096
#define ATT_SCALE 0.125f            // HD^-0.5
#define LOG2E_SCALE 0.1803368801111f // ATT_SCALE * log2(e)

typedef _Float16 f16;
typedef f16   f16x8 __attribute__((ext_vector_type(8)));
typedef float f32x4 __attribute__((ext_vector_type(4)));

// async global->LDS, 16B per lane; LDS dest = wave-uniform base + lane*16
__device__ __forceinline__ void gload16(const void* g, void* l) {
  __builtin_amdgcn_global_load_lds(
      (const __attribute__((address_space(1))) void*)g,
      (__attribute__((address_space(3))) void*)l, 16, 0, 0);
}

// ---------------------------------------------------------------------------
// Fused weight transposes: W [K,N] f32 -> Wt [N,K] f16 for all 7 weights.
struct WtAll {
  const float* src[7];
  f16*         dst[7];
};
__global__ __launch_bounds__(256) void wt_all_kernel(WtAll a)
{
  const int bid = blockIdx.x;
  // order: qkv(768) kv(512) sa(256) q(256) ca(256) fc1(1024) fc2(1024)
  int m, base, N, K;
  if      (bid < 768)  { m = 0; base = 0;    N = 3072; K = 1024; }
  else if (bid < 1280) { m = 1; base = 768;  N = 2048; K = 1024; }
  else if (bid < 1536) { m = 2; base = 1280; N = 1024; K = 1024; }
  else if (bid < 1792) { m = 3; base = 1536; N = 1024; K = 1024; }
  else if (bid < 2048) { m = 4; base = 1792; N = 1024; K = 1024; }
  else if (bid < 3072) { m = 5; base = 2048; N = 4096; K = 1024; }
  else                 { m = 6; base = 3072; N = 1024; K = 4096; }
  const float* W = a.src[m];
  f16* Wt = a.dst[m];
  const int local = bid - base;
  const int tx = N >> 6;
  const int bx = local % tx, by = local / tx;

  __shared__ f16 tile[64][72];
  const int t = threadIdx.x;
  const int k0 = by * 64, n0 = bx * 64;
  const int kr = t >> 4, nc = (t & 15) * 4;
#pragma unroll
  for (int p = 0; p < 4; ++p) {
    f32x4 v = *(const f32x4*)&W[(size_t)(k0 + kr + p * 16) * N + n0 + nc];
#pragma unroll
    for (int j = 0; j < 4; ++j) tile[nc + j][kr + p * 16] = (f16)v[j];
  }
  __syncthreads();
  const int nr = t >> 2, ck = (t & 3) * 16;
  *(f16x8*)&Wt[(size_t)(n0 + nr) * K + k0 + ck]     = *(const f16x8*)&tile[nr][ck];
  *(f16x8*)&Wt[(size_t)(n0 + nr) * K + k0 + ck + 8] = *(const f16x8*)&tile[nr][ck + 8];
}

// ---------------------------------------------------------------------------
// mod = silu(t_emb) @ adaln_w + adaln_b     [B, 6D] fp32
__global__ __launch_bounds__(256) void mod_kernel(
    const float* __restrict__ t_emb, const float* __restrict__ w,
    const float* __restrict__ bias, float* __restrict__ mod)
{
  __shared__ float s[D_MODEL];
  const int b = blockIdx.y;
  for (int i = threadIdx.x; i < D_MODEL; i += 256) {
    float v = t_emb[b * D_MODEL + i];
    s[i] = v / (1.f + expf(-v));
  }
  __syncthreads();
  const int col = blockIdx.x * 256 + threadIdx.x;
  float acc = 0.f;
  for (int k = 0; k < D_MODEL; ++k) acc += s[k] * w[(size_t)k * (6 * D_MODEL) + col];
  mod[(size_t)b * (6 * D_MODEL) + col] = acc + bias[col];
}

// ---------------------------------------------------------------------------
// Fused: X = x (f32, first 16384 blocks) ; ctxh = f16(ctx) (rest)
#define CTX_ELE (BATCH * SEQ_S * D_MODEL)   // 315,392
__global__ __launch_bounds__(256) void initcvt_kernel(
    const float* __restrict__ x, float* __restrict__ X,
    const float* __restrict__ ctx, f16* __restrict__ ctxh)
{
  const int i = blockIdx.x * 256 + threadIdx.x;
  if (blockIdx.x < 16384) {
    X[i] = x[i];
  } else {
    const int j = i - 16384 * 256;
    if (j < CTX_ELE) ctxh[j] = (f16)ctx[j];
  }
}

// ---------------------------------------------------------------------------
// out = LN(X) * (1 + mod[b, scale_off + i]) + mod[b, shift_off + i]   (mod nullable)
__global__ __launch_bounds__(256) void lnmod_kernel(
    const float* __restrict__ X, const float* __restrict__ mod,
    int scale_off, int shift_off, f16* __restrict__ out)
{
  const int row = blockIdx.x;
  const int b = row >> 10;           // 1024 rows per batch
  const float* xr = X + (size_t)row * D_MODEL;
  float s = 0.f, s2 = 0.f;
  for (int i = threadIdx.x; i < D_MODEL; i += 256) {
    float v = xr[i]; s += v; s2 += v * v;
  }
  const int lane = threadIdx.x & 63, w = threadIdx.x >> 6;
  for (int o = 32; o; o >>= 1) { s += __shfl_xor(s, o); s2 += __shfl_xor(s2, o); }
  __shared__ float rs[4], rs2[4];
  if (lane == 0) { rs[w] = s; rs2[w] = s2; }
  __syncthreads();
  s = rs[0] + rs[1] + rs[2] + rs[3];
  s2 = rs2[0] + rs2[1] + rs2[2] + rs2[3];
  const float mean = s * (1.f / D_MODEL);
  const float var = s2 * (1.f / D_MODEL) - mean * mean;
  const float rstd = rsqrtf(var + 1e-6f);
  const float* mrow = mod ? mod + (size_t)b * (6 * D_MODEL) : nullptr;
  for (int i = threadIdx.x; i < D_MODEL; i += 256) {
    float v = (xr[i] - mean) * rstd;
    if (mrow) v = v * (1.f + mrow[scale_off + i]) + mrow[shift_off + i];
    out[(size_t)row * D_MODEL + i] = (f16)v;
  }
}

// ---------------------------------------------------------------------------
// C = A[M,K](f16) @ Wt[N,K](f16)^T + bias(f32); optional GELU;
// optional residual X += gate*C; writes f16 (outb) and/or f32 (outf).
// 128xBN tile, BK in {32,64}, 4 waves (2x2).
// Staging: global_load_lds 16B, linear LDS dest + pre-swizzled global source;
// reads use matching XOR slot swizzle (bank-balanced, verified 2-way).
// PIPE-deep pipeline with COUNTED vmcnt; ONE barrier per K-step; XCD swizzle.
// BK=64 halves the per-K-step sync overhead (the round-12 proven lever).
template <int BN, int BK, int PIPE>
__global__ __launch_bounds__(256) void gemm_kernel(
    const f16* __restrict__ A, const f16* __restrict__ Wt,
    const float* __restrict__ bias,
    float* __restrict__ Xres, const float* __restrict__ gate,
    f16* __restrict__ outb, float* __restrict__ outf,
    int M, int N, int K, int do_gelu)
{
  constexpr int NB = BN / 32;                    // acc cols per wave
  constexpr int KB = BK / 32;                    // K sub-steps per tile
  constexpr int L  = (128 + BN) * BK / 2048;     // gload_lds per tile per thread
  constexpr int WV = (PIPE - 2) * L;             // vmcnt target
  __shared__ f16 As[PIPE][128 * BK];
  __shared__ f16 Bs[PIPE][BN * BK];
  const int t = threadIdx.x;
  const int lane = t & 63, wave = t >> 6;
  const int wr = wave >> 1, wc = wave & 1;
  int bx = blockIdx.x, by = blockIdx.y;
  {
    const int gx = gridDim.x;
    const int nwg = gx * gridDim.y;
    if ((nwg & 7) == 0) {
      int wg = by * gx + bx;
      wg = (wg & 7) * (nwg >> 3) + (wg >> 3);
      bx = wg % gx; by = wg / gx;
    }
  }
  const int brow = by * 128, bcol = bx * BN;
  const int fr = lane & 15, fq = lane >> 4;
  const int ldsoff = wave * 512;

  int sr, sc;
  if constexpr (BK == 32) {
    sr = t >> 2;                                   // 64 rows per pass
    sc = (((t & 3) ^ ((sr & 3) ^ ((sr >> 2) & 3))) * 8);
  } else {
    sr = t >> 3;                                   // 32 rows per pass
    sc = (((t & 7) ^ (sr & 7)) * 8);
  }

  f32x4 acc[4][NB] = {};
  const f16* Ag = A  + (size_t)(brow + sr) * K + sc;
  const f16* Bg = Wt + (size_t)(bcol + sr) * K + sc;
  const int nt = K / BK;

  auto STAGE = [&](int buf, int k0) {
    if constexpr (BK == 32) {
      gload16(Ag + k0,                  &As[buf][ldsoff]);
      gload16(Ag + (size_t)64 * K + k0, &As[buf][2048 + ldsoff]);
      gload16(Bg + k0,                  &Bs[buf][ldsoff]);
      if constexpr (BN == 128)
        gload16(Bg + (size_t)64 * K + k0, &Bs[buf][2048 + ldsoff]);
    } else {
      gload16(Ag + k0,                  &As[buf][ldsoff]);
      gload16(Ag + (size_t)32 * K + k0, &As[buf][2048 + ldsoff]);
      gload16(Ag + (size_t)64 * K + k0, &As[buf][4096 + ldsoff]);
      gload16(Ag + (size_t)96 * K + k0, &As[buf][6144 + ldsoff]);
      gload16(Bg + k0,                  &Bs[buf][ldsoff]);     // BN==64 only
      gload16(Bg + (size_t)32 * K + k0, &Bs[buf][2048 + ldsoff]);
    }
  };

  const int rsw32 = (((fr & 3) ^ ((fr >> 2) & 3)) * 8);  // BK=32 read swizzle

  for (int i = 0; i < PIPE - 1 && i < nt; ++i) STAGE(i, i * BK);
  int cur = 0;
  for (int kt = 0; kt < nt; ++kt) {
    if constexpr (WV == 3)
      asm volatile("s_waitcnt vmcnt(3)\n\ts_barrier" ::: "memory");
    else if constexpr (WV == 4)
      asm volatile("s_waitcnt vmcnt(4)\n\ts_barrier" ::: "memory");
    else if constexpr (WV == 6)
      asm volatile("s_waitcnt vmcnt(6)\n\ts_barrier" ::: "memory");
    else if constexpr (WV == 8)
      asm volatile("s_waitcnt vmcnt(8)\n\ts_barrier" ::: "memory");
    else if constexpr (WV == 12)
      asm volatile("s_waitcnt vmcnt(12)\n\ts_barrier" ::: "memory");
    else
      asm volatile("s_waitcnt vmcnt(0)\n\ts_barrier" ::: "memory");
    int nx = cur + PIPE - 1; if (nx >= PIPE) nx -= PIPE;
    if (kt + PIPE - 1 < nt) STAGE(nx, (kt + PIPE - 1) * BK);

    if constexpr (BK == 32) {
      f16x8 af[4], bf[NB];
#pragma unroll
      for (int m = 0; m < 4; ++m)
        af[m] = *(const f16x8*)&As[cur][(wr * 64 + m * 16 + fr) * 32 + ((fq * 8) ^ rsw32)];
#pragma unroll
      for (int n = 0; n < NB; ++n)
        bf[n] = *(const f16x8*)&Bs[cur][(wc * (BN / 2) + n * 16 + fr) * 32 + ((fq * 8) ^ rsw32)];
#pragma unroll
      for (int m = 0; m < 4; ++m)
#pragma unroll
        for (int n = 0; n < NB; ++n)
          acc[m][n] = __builtin_amdgcn_mfma_f32_16x16x32_f16(af[m], bf[n], acc[m][n], 0, 0, 0);
    } else {
      f16x8 af[4][KB], bf[NB][KB];
#pragma unroll
      for (int m = 0; m < 4; ++m) {
        const int ra = wr * 64 + m * 16 + fr;
#pragma unroll
        for (int kk = 0; kk < KB; ++kk)
          af[m][kk] = *(const f16x8*)&As[cur][ra * 64 + (((kk * 4 + fq) ^ (ra & 7)) * 8)];
      }
#pragma unroll
      for (int n = 0; n < NB; ++n) {
        const int rb = wc * (BN / 2) + n * 16 + fr;
#pragma unroll
        for (int kk = 0; kk < KB; ++kk)
          bf[n][kk] = *(const f16x8*)&Bs[cur][rb * 64 + (((kk * 4 + fq) ^ (rb & 7)) * 8)];
      }
#pragma unroll
      for (int kk = 0; kk < KB; ++kk)
#pragma unroll
        for (int m = 0; m < 4; ++m)
#pragma unroll
          for (int n = 0; n < NB; ++n)
            acc[m][n] = __builtin_amdgcn_mfma_f32_16x16x32_f16(af[m][kk], bf[n][kk], acc[m][n], 0, 0, 0);
    }
    ++cur; if (cur == PIPE) cur = 0;
  }

#pragma unroll
  for (int m = 0; m < 4; ++m) {
#pragma unroll
    for (int n = 0; n < NB; ++n) {
      const int col = bcol + wc * (BN / 2) + n * 16 + fr;
      const int row0 = brow + wr * 64 + m * 16 + fq * 4;
      const float bv = bias ? bias[col] : 0.f;
#pragma unroll
      for (int r = 0; r < 4; ++r) {
        const int row = row0 + r;
        if (row >= M) continue;
        float v = acc[m][n][r] + bv;
        if (do_gelu) {
          // gelu_tanh(u) == u * sigmoid(2c(u+0.044715u^3)); sigmoid via exp2
          float u = v;
          float z = u + 0.044715f * u * u * u;
          v = u / (1.f + exp2f(-2.3022083f * z));
        }
        if (Xres) {
          const float g = gate ? gate[(size_t)(row >> 10) * (6 * D_MODEL) + col] : 1.0f;
          v = Xres[(size_t)row * N + col] + g * v;
          Xres[(size_t)row * N + col] = v;
        }
        if (outb) outb[(size_t)row * N + col] = (f16)v;
        if (outf) outf[(size_t)row * N + col] = v;
      }
    }
  }
}

// ---------------------------------------------------------------------------
// MFMA flash self-attention over qkv buffer [B*N, 3D] (col = which*1024+h*64+d).
// grid (N/64, H, B), block 256 = 4 waves; wave w owns q-rows qt*64+w*16..+16.
__global__ __launch_bounds__(256) void sa_attn_kernel(
    const f16* __restrict__ qkv, f16* __restrict__ out)
{
  const int qt = blockIdx.x, h = blockIdx.y, b = blockIdx.z;
  __shared__ f16 Kl[64][72];      // [s][d]
  __shared__ f16 Vt[64][72];      // [d][s] transposed
  __shared__ f16 Pl[4][16][72];   // per-wave P strip [q_local][s]
  const int t = threadIdx.x;
  const int lane = t & 63, w = t >> 6;
  const int fr = lane & 15, fq = lane >> 4;
  const size_t base = (size_t)b * SEQ_N * 3072 + h * 64;

  const int qrow = qt * 64 + w * 16 + fr;
  f16x8 qa[2];
#pragma unroll
  for (int kk = 0; kk < 2; ++kk) {
    qa[kk] = *(const f16x8*)&qkv[base + (size_t)qrow * 3072 + kk * 32 + fq * 8];
#pragma unroll
    for (int j = 0; j < 8; ++j)
      qa[kk][j] = (f16)((float)qa[kk][j] * LOG2E_SCALE);
  }

  f32x4 o_acc[4] = {};
  float m_run[4], l_run[4];
#pragma unroll
  for (int r = 0; r < 4; ++r) { m_run[r] = -1e30f; l_run[r] = 0.f; }

  const int ksr = t >> 2, ksc = (t & 3) * 8;   // K: 64 rows x 4 chunks, vector
  const int vs = t & 63, vd = (t >> 6) * 16;   // V: per-wave one d-group, all s
  f16x8 kreg0, kreg1, vreg0, vreg1;

  auto LOADKV = [&](int s0) {
    kreg0 = *(const f16x8*)&qkv[base + (size_t)(s0 + ksr) * 3072 + 1024 + ksc];
    kreg1 = *(const f16x8*)&qkv[base + (size_t)(s0 + ksr) * 3072 + 1024 + ksc + 32];
    vreg0 = *(const f16x8*)&qkv[base + (size_t)(s0 + vs) * 3072 + 2048 + vd];
    vreg1 = *(const f16x8*)&qkv[base + (size_t)(s0 + vs) * 3072 + 2048 + vd + 8];
  };

  LOADKV(0);
  for (int s0 = 0; s0 < SEQ_N; s0 += 64) {
    __syncthreads();
    *(f16x8*)&Kl[ksr][ksc]      = kreg0;
    *(f16x8*)&Kl[ksr][ksc + 32] = kreg1;
#pragma unroll
    for (int j = 0; j < 8; ++j) {
      Vt[vd + j][vs]     = vreg0[j];
      Vt[vd + 8 + j][vs] = vreg1[j];
    }
    __syncthreads();
    if (s0 + 64 < SEQ_N) LOADKV(s0 + 64);

    f32x4 sf[4] = {};
#pragma unroll
    for (int kk = 0; kk < 2; ++kk) {
#pragma unroll
      for (int n = 0; n < 4; ++n) {
        f16x8 kb = *(const f16x8*)&Kl[n * 16 + fr][kk * 32 + fq * 8];
        sf[n] = __builtin_amdgcn_mfma_f32_16x16x32_f16(qa[kk], kb, sf[n], 0, 0, 0);
      }
    }

#pragma unroll
    for (int r = 0; r < 4; ++r) {
      float v = fmaxf(fmaxf(sf[0][r], sf[1][r]), fmaxf(sf[2][r], sf[3][r]));
#pragma unroll
      for (int o = 1; o < 16; o <<= 1) v = fmaxf(v, __shfl_xor(v, o));
      const float mn = fmaxf(m_run[r], v);
      const float f = exp2f(m_run[r] - mn);
      m_run[r] = mn;
#pragma unroll
      for (int n = 0; n < 4; ++n) o_acc[n][r] *= f;
      float rs = 0.f;
#pragma unroll
      for (int n = 0; n < 4; ++n) {
        float p = exp2f(sf[n][r] - mn);
        sf[n][r] = p;
        rs += p;
      }
      l_run[r] = l_run[r] * f + rs;
    }

#pragma unroll
    for (int n = 0; n < 4; ++n)
#pragma unroll
      for (int r = 0; r < 4; ++r)
        Pl[w][fq * 4 + r][n * 16 + fr] = (f16)sf[n][r];

#pragma unroll
    for (int kk = 0; kk < 2; ++kk) {
      f16x8 pa = *(const f16x8*)&Pl[w][fr][kk * 32 + fq * 8];
#pragma unroll
      for (int n = 0; n < 4; ++n) {
        f16x8 vb = *(const f16x8*)&Vt[n * 16 + fr][kk * 32 + fq * 8];
        o_acc[n] = __builtin_amdgcn_mfma_f32_16x16x32_f16(pa, vb, o_acc[n], 0, 0, 0);
      }
    }
  }

  const size_t orow = (size_t)(b * SEQ_N + qt * 64 + w * 16) * D_MODEL + h * 64;
#pragma unroll
  for (int r = 0; r < 4; ++r) {
    float l = l_run[r];
#pragma unroll
    for (int o = 1; o < 16; o <<= 1) l += __shfl_xor(l, o);
    const float inv = 1.f / l;
#pragma unroll
    for (int n = 0; n < 4; ++n)
      out[orow + (size_t)(fq * 4 + r) * D_MODEL + n * 16 + fr] = (f16)(o_acc[n][r] * inv);
  }
}

// ---------------------------------------------------------------------------
// Cross-attention: q [B*N, D], kv [B*S, 2D] (col = which*1024 + h*64 + d).
__global__ __launch_bounds__(256) void ca_attn_kernel(
    const f16* __restrict__ qb, const f16* __restrict__ kvb,
    f16* __restrict__ out)
{
  const int qt = blockIdx.x, h = blockIdx.y, b = blockIdx.z;
  __shared__ float qs[16][68];
  __shared__ float sc[16][80];
  __shared__ f16 kt[77][72];
  __shared__ f16 vt[77][72];
  const int t = threadIdx.x;
  for (int i = t; i < 16 * 64; i += 256) {
    int q = i >> 6, d = i & 63;
    qs[q][d] = (float)qb[(size_t)(b * SEQ_N + qt * 16 + q) * D_MODEL + h * 64 + d];
  }
  for (int i = t; i < SEQ_S * 8; i += 256) {
    int r = i >> 3, c = (i & 7) * 8;
    *(f16x8*)&kt[r][c] = *(const f16x8*)&kvb[(size_t)(b * SEQ_S + r) * 2048 + h * 64 + c];
    *(f16x8*)&vt[r][c] = *(const f16x8*)&kvb[(size_t)(b * SEQ_S + r) * 2048 + 1024 + h * 64 + c];
  }
  __syncthreads();
  for (int idx = t; idx < 16 * 80; idx += 256) {
    int q = idx / 80, s = idx % 80;
    float a = -1e30f;
    if (s < SEQ_S) {
      a = 0.f;
      for (int d = 0; d < 64; ++d) a += qs[q][d] * (float)kt[s][d];
      a *= LOG2E_SCALE;
    }
    sc[q][s] = a;
  }
  __syncthreads();
  const int lane = t & 63, w = t >> 6;
  for (int q = w; q < 16; q += 4) {
    float m = -1e30f;
    for (int j = lane; j < 80; j += 64) m = fmaxf(m, sc[q][j]);
    for (int o = 32; o; o >>= 1) m = fmaxf(m, __shfl_xor(m, o));
    float sum = 0.f;
    for (int j = lane; j < 80; j += 64) {
      float e = (j < SEQ_S) ? exp2f(sc[q][j] - m) : 0.f;
      sc[q][j] = e; sum += e;
    }
    for (int o = 32; o; o >>= 1) sum += __shfl_xor(sum, o);
    float inv = 1.f / sum;
    for (int j = lane; j < 80; j += 64) sc[q][j] *= inv;
  }
  __syncthreads();
  const int q = t >> 4, d0 = (t & 15) * 4;
  float a0 = 0, a1 = 0, a2 = 0, a3 = 0;
  for (int s = 0; s < SEQ_S; ++s) {
    float p = sc[q][s];
    a0 += p * (float)vt[s][d0];
    a1 += p * (float)vt[s][d0 + 1];
    a2 += p * (float)vt[s][d0 + 2];
    a3 += p * (float)vt[s][d0 + 3];
  }
  size_t orow = (size_t)(b * SEQ_N + qt * 16 + q) * D_MODEL + h * 64;
  out[orow + d0] = (f16)a0;
  out[orow + d0 + 1] = (f16)a1;
  out[orow + d0 + 2] = (f16)a2;
  out[orow + d0 + 3] = (f16)a3;
}

// ---------------------------------------------------------------------------
extern "C" void kernel_launch(void* const* d_in, const int* in_sizes, int n_in,
                              void* d_out, int out_size, void* d_ws, size_t ws_size,
                              hipStream_t stream)
{
  const float* x       = (const float*)d_in[0];
  const float* t_emb   = (const float*)d_in[1];
  const float* ctx     = (const float*)d_in[2];
  const float* adaln_w = (const float*)d_in[3];
  const float* adaln_b = (const float*)d_in[4];
  const float* qkv_w   = (const float*)d_in[5];
  const float* qkv_b   = (const float*)d_in[6];
  const float* sa_pw   = (const float*)d_in[7];
  const float* sa_pb   = (const float*)d_in[8];
  const float* q_w     = (const float*)d_in[9];
  const float* q_b     = (const float*)d_in[10];
  const float* kv_w    = (const float*)d_in[11];
  const float* kv_b    = (const float*)d_in[12];
  const float* ca_pw   = (const float*)d_in[13];
  const float* ca_pb   = (const float*)d_in[14];
  const float* fc1_w   = (const float*)d_in[15];
  const float* fc1_b   = (const float*)d_in[16];
  const float* fc2_w   = (const float*)d_in[17];
  const float* fc2_b   = (const float*)d_in[18];
  float* out = (float*)d_out;

  // ---- workspace layout (all regions DISJOINT) ----
  char* ws = (char*)d_ws;
  float* mod    = (float*)(ws + 0);            //    98,304 B  [B,6D] f32
  float* X      = (float*)(ws + 98304);        // 16,777,216 B residual f32
  f16*   bufA   = (f16*)(ws + 16875520);       //  8,388,608 B (xm / xn / xm_ff)
  f16*   bufB   = (f16*)(ws + 25264128);       // 25,165,824 B (qkv / q / h)
  f16*   bufC   = (f16*)(ws + 50429952);       //  8,388,608 B (attn out)
  f16*   bufKV  = (f16*)(ws + 58818560);       //  1,261,568 B (kv, 308x2048)
  f16*   ctxh   = (f16*)(ws + 60080128);       //    786,432 B (ctx f16, PADDED to 384 rows)
  f16*   qkv_wt = (f16*)(ws + 60866560);       //  6,291,456 B [3072][1024]
  f16*   kv_wt  = (f16*)(ws + 67158016);       //  4,194,304 B [2048][1024]
  f16*   sa_pwt = (f16*)(ws + 71352320);       //  2,097,152 B [1024][1024]
  f16*   q_wt   = (f16*)(ws + 73449472);       //  2,097,152 B
  f16*   ca_pwt = (f16*)(ws + 75546624);       //  2,097,152 B
  f16*   fc1_wt = (f16*)(ws + 77643776);       //  8,388,608 B [4096][1024]
  f16*   fc2_wt = (f16*)(ws + 86032384);       //  8,388,608 B [1024][4096]
  f16*   bufQ   = bufB;                         // total 94,420,992 B

  const dim3 blk(256);
  const int TOK = BATCH * SEQ_N;  // 4096

  // ---- fused weight transposes (f32 [K,N] -> f16 [N,K]) ----
  WtAll wa;
  wa.src[0] = qkv_w; wa.dst[0] = qkv_wt;
  wa.src[1] = kv_w;  wa.dst[1] = kv_wt;
  wa.src[2] = sa_pw; wa.dst[2] = sa_pwt;
  wa.src[3] = q_w;   wa.dst[3] = q_wt;
  wa.src[4] = ca_pw; wa.dst[4] = ca_pwt;
  wa.src[5] = fc1_w; wa.dst[5] = fc1_wt;
  wa.src[6] = fc2_w; wa.dst[6] = fc2_wt;
  wt_all_kernel<<<dim3(4096), blk, 0, stream>>>(wa);

  // AdaLN modulation params
  mod_kernel<<<dim3(24, BATCH), blk, 0, stream>>>(t_emb, adaln_w, adaln_b, mod);
  // X = x (f32) ; ctx -> f16   (fused)
  initcvt_kernel<<<dim3(16384 + (CTX_ELE + 255) / 256), blk, 0, stream>>>(
      x, X, ctx, ctxh);

  // --- self-attention branch ---  offsets: sh_sa=0, sc_sa=1024, g_sa=2048
  lnmod_kernel<<<TOK, blk, 0, stream>>>(X, mod, 1024, 0, bufA);
  gemm_kernel<64, 64, 3><<<dim3(3072 / 64, TOK / 128), blk, 0, stream>>>(
      bufA, qkv_wt, qkv_b, nullptr, nullptr, bufB, nullptr, TOK, 3072, 1024, 0);
  // kv gemm (M=308; A buffer padded to 384 readable rows)
  gemm_kernel<64, 64, 3><<<dim3(2048 / 64, 3), blk, 0, stream>>>(
      ctxh, kv_wt, kv_b, nullptr, nullptr, bufKV, nullptr, BATCH * SEQ_S, 2048, 1024, 0);
  sa_attn_kernel<<<dim3(SEQ_N / 64, NHEAD, BATCH), blk, 0, stream>>>(bufB, bufC);
  gemm_kernel<64, 64, 3><<<dim3(1024 / 64, TOK / 128), blk, 0, stream>>>(
      bufC, sa_pwt, sa_pb, X, mod + 2048, nullptr, nullptr, TOK, 1024, 1024, 0);

  // --- cross-attention branch ---
  lnmod_kernel<<<TOK, blk, 0, stream>>>(X, nullptr, 0, 0, bufA);
  gemm_kernel<64, 64, 3><<<dim3(1024 / 64, TOK / 128), blk, 0, stream>>>(
      bufA, q_wt, q_b, nullptr, nullptr, bufQ, nullptr, TOK, 1024, 1024, 0);
  ca_attn_kernel<<<dim3(SEQ_N / 16, NHEAD, BATCH), blk, 0, stream>>>(bufQ, bufKV, bufC);
  gemm_kernel<64, 64, 3><<<dim3(1024 / 64, TOK / 128), blk, 0, stream>>>(
      bufC, ca_pwt, ca_pb, X, nullptr, nullptr, nullptr, TOK, 1024, 1024, 0);

  // --- MLP branch ---  offsets: sh_ff=3072, sc_ff=4096, g_ff=5120
  lnmod_kernel<<<TOK, blk, 0, stream>>>(X, mod, 4096, 3072, bufA);
  gemm_kernel<64, 64, 3><<<dim3(MLP_DIM / 64, TOK / 128), blk, 0, stream>>>(
      bufA, fc1_wt, fc1_b, nullptr, nullptr, bufB, nullptr, TOK, MLP_DIM, 1024, 1);
  gemm_kernel<64, 64, 3><<<dim3(1024 / 64, TOK / 128), blk, 0, stream>>>(
      bufB, fc2_wt, fc2_b, X, mod + 5120, nullptr, out, TOK, 1024, MLP_DIM, 0);
}

// Round 14
// 473.572 us; speedup vs baseline: 1.0638x; 1.0638x over previous
//
#include <hip/hip_runtime.h>
#include <hip/hip_bf16.h>

// VS_DiT_Block: AdaLN-modulated DiT block (self-attn + cross-attn + MLP)
// B=4, N=1024, D=1024, H=16, HD=64, S=77, MLP=4096. f32 I/O, fp16 MFMA compute,
// f32 residual chain. Weights pre-transposed to f16 W^T[N][K] once per launch.

#define D_MODEL 1024
#define NHEAD   16
#define HDIM    64
#define SEQ_N   1024
#define SEQ_S   77
#define BATCH   4
#define MLP_DIM 4096
#define ATT_SCALE 0.125f            // HD^-0.5
#define LOG2E_SCALE 0.1803368801111f // ATT_SCALE * log2(e)

typedef _Float16 f16;
typedef f16   f16x8 __attribute__((ext_vector_type(8)));
typedef float f32x4 __attribute__((ext_vector_type(4)));

// async global->LDS, 16B per lane; LDS dest = wave-uniform base + lane*16
__device__ __forceinline__ void gload16(const void* g, void* l) {
  __builtin_amdgcn_global_load_lds(
      (const __attribute__((address_space(1))) void*)g,
      (__attribute__((address_space(3))) void*)l, 16, 0, 0);
}

// ---------------------------------------------------------------------------
// Fused weight transposes: W [K,N] f32 -> Wt [N,K] f16 for all 7 weights.
struct WtAll {
  const float* src[7];
  f16*         dst[7];
};
__global__ __launch_bounds__(256) void wt_all_kernel(WtAll a)
{
  const int bid = blockIdx.x;
  // order: qkv(768) kv(512) sa(256) q(256) ca(256) fc1(1024) fc2(1024)
  int m, base, N, K;
  if      (bid < 768)  { m = 0; base = 0;    N = 3072; K = 1024; }
  else if (bid < 1280) { m = 1; base = 768;  N = 2048; K = 1024; }
  else if (bid < 1536) { m = 2; base = 1280; N = 1024; K = 1024; }
  else if (bid < 1792) { m = 3; base = 1536; N = 1024; K = 1024; }
  else if (bid < 2048) { m = 4; base = 1792; N = 1024; K = 1024; }
  else if (bid < 3072) { m = 5; base = 2048; N = 4096; K = 1024; }
  else                 { m = 6; base = 3072; N = 1024; K = 4096; }
  const float* W = a.src[m];
  f16* Wt = a.dst[m];
  const int local = bid - base;
  const int tx = N >> 6;
  const int bx = local % tx, by = local / tx;

  __shared__ f16 tile[64][72];
  const int t = threadIdx.x;
  const int k0 = by * 64, n0 = bx * 64;
  const int kr = t >> 4, nc = (t & 15) * 4;
#pragma unroll
  for (int p = 0; p < 4; ++p) {
    f32x4 v = *(const f32x4*)&W[(size_t)(k0 + kr + p * 16) * N + n0 + nc];
#pragma unroll
    for (int j = 0; j < 4; ++j) tile[nc + j][kr + p * 16] = (f16)v[j];
  }
  __syncthreads();
  const int nr = t >> 2, ck = (t & 3) * 16;
  *(f16x8*)&Wt[(size_t)(n0 + nr) * K + k0 + ck]     = *(const f16x8*)&tile[nr][ck];
  *(f16x8*)&Wt[(size_t)(n0 + nr) * K + k0 + ck + 8] = *(const f16x8*)&tile[nr][ck + 8];
}

// ---------------------------------------------------------------------------
// mod = silu(t_emb) @ adaln_w + adaln_b     [B, 6D] fp32
__global__ __launch_bounds__(256) void mod_kernel(
    const float* __restrict__ t_emb, const float* __restrict__ w,
    const float* __restrict__ bias, float* __restrict__ mod)
{
  __shared__ float s[D_MODEL];
  const int b = blockIdx.y;
  for (int i = threadIdx.x; i < D_MODEL; i += 256) {
    float v = t_emb[b * D_MODEL + i];
    s[i] = v / (1.f + expf(-v));
  }
  __syncthreads();
  const int col = blockIdx.x * 256 + threadIdx.x;
  float acc = 0.f;
  for (int k = 0; k < D_MODEL; ++k) acc += s[k] * w[(size_t)k * (6 * D_MODEL) + col];
  mod[(size_t)b * (6 * D_MODEL) + col] = acc + bias[col];
}

// ---------------------------------------------------------------------------
// Fused: X = x (f32, first 16384 blocks) ; ctxh = f16(ctx) (rest)
#define CTX_ELE (BATCH * SEQ_S * D_MODEL)   // 315,392
__global__ __launch_bounds__(256) void initcvt_kernel(
    const float* __restrict__ x, float* __restrict__ X,
    const float* __restrict__ ctx, f16* __restrict__ ctxh)
{
  const int i = blockIdx.x * 256 + threadIdx.x;
  if (blockIdx.x < 16384) {
    X[i] = x[i];
  } else {
    const int j = i - 16384 * 256;
    if (j < CTX_ELE) ctxh[j] = (f16)ctx[j];
  }
}

// ---------------------------------------------------------------------------
// out = LN(X) * (1 + mod[b, scale_off + i]) + mod[b, shift_off + i]   (mod nullable)
__global__ __launch_bounds__(256) void lnmod_kernel(
    const float* __restrict__ X, const float* __restrict__ mod,
    int scale_off, int shift_off, f16* __restrict__ out)
{
  const int row = blockIdx.x;
  const int b = row >> 10;           // 1024 rows per batch
  const float* xr = X + (size_t)row * D_MODEL;
  float s = 0.f, s2 = 0.f;
  for (int i = threadIdx.x; i < D_MODEL; i += 256) {
    float v = xr[i]; s += v; s2 += v * v;
  }
  const int lane = threadIdx.x & 63, w = threadIdx.x >> 6;
  for (int o = 32; o; o >>= 1) { s += __shfl_xor(s, o); s2 += __shfl_xor(s2, o); }
  __shared__ float rs[4], rs2[4];
  if (lane == 0) { rs[w] = s; rs2[w] = s2; }
  __syncthreads();
  s = rs[0] + rs[1] + rs[2] + rs[3];
  s2 = rs2[0] + rs2[1] + rs2[2] + rs2[3];
  const float mean = s * (1.f / D_MODEL);
  const float var = s2 * (1.f / D_MODEL) - mean * mean;
  const float rstd = rsqrtf(var + 1e-6f);
  const float* mrow = mod ? mod + (size_t)b * (6 * D_MODEL) : nullptr;
  for (int i = threadIdx.x; i < D_MODEL; i += 256) {
    float v = (xr[i] - mean) * rstd;
    if (mrow) v = v * (1.f + mrow[scale_off + i]) + mrow[shift_off + i];
    out[(size_t)row * D_MODEL + i] = (f16)v;
  }
}

// ---------------------------------------------------------------------------
// C = A[M,K](f16) @ Wt[N,K](f16)^T + bias(f32); optional GELU;
// optional residual X += gate*C; writes f16 (outb) and/or f32 (outf).
// 128xBN tile, BK in {32,64}, 4 waves (2x2).
// Staging: global_load_lds 16B, linear LDS dest + pre-swizzled global source;
// reads use matching XOR slot swizzle (bank-balanced, verified 2-way).
// PIPE-deep pipeline with COUNTED vmcnt; ONE barrier per K-step; XCD swizzle.
// Proven configs: <128,32,3> for wide-N (reuse-bound), <64,64,3> for N=1024
// (sync-bound), <128,64,2> experimental (same reuse as <128,32>, half the
// barriers, vmcnt(0) drain).
template <int BN, int BK, int PIPE>
__global__ __launch_bounds__(256) void gemm_kernel(
    const f16* __restrict__ A, const f16* __restrict__ Wt,
    const float* __restrict__ bias,
    float* __restrict__ Xres, const float* __restrict__ gate,
    f16* __restrict__ outb, float* __restrict__ outf,
    int M, int N, int K, int do_gelu)
{
  constexpr int NB = BN / 32;                    // acc cols per wave
  constexpr int KB = BK / 32;                    // K sub-steps per tile
  constexpr int L  = (128 + BN) * BK / 2048;     // gload_lds per tile per thread
  constexpr int WV = (PIPE - 2) * L;             // vmcnt target
  __shared__ f16 As[PIPE][128 * BK];
  __shared__ f16 Bs[PIPE][BN * BK];
  const int t = threadIdx.x;
  const int lane = t & 63, wave = t >> 6;
  const int wr = wave >> 1, wc = wave & 1;
  int bx = blockIdx.x, by = blockIdx.y;
  {
    const int gx = gridDim.x;
    const int nwg = gx * gridDim.y;
    if ((nwg & 7) == 0) {
      int wg = by * gx + bx;
      wg = (wg & 7) * (nwg >> 3) + (wg >> 3);
      bx = wg % gx; by = wg / gx;
    }
  }
  const int brow = by * 128, bcol = bx * BN;
  const int fr = lane & 15, fq = lane >> 4;
  const int ldsoff = wave * 512;

  int sr, sc;
  if constexpr (BK == 32) {
    sr = t >> 2;                                   // 64 rows per pass
    sc = (((t & 3) ^ ((sr & 3) ^ ((sr >> 2) & 3))) * 8);
  } else {
    sr = t >> 3;                                   // 32 rows per pass
    sc = (((t & 7) ^ (sr & 7)) * 8);
  }

  f32x4 acc[4][NB] = {};
  const f16* Ag = A  + (size_t)(brow + sr) * K + sc;
  const f16* Bg = Wt + (size_t)(bcol + sr) * K + sc;
  const int nt = K / BK;

  auto STAGE = [&](int buf, int k0) {
    if constexpr (BK == 32) {
      gload16(Ag + k0,                  &As[buf][ldsoff]);
      gload16(Ag + (size_t)64 * K + k0, &As[buf][2048 + ldsoff]);
      gload16(Bg + k0,                  &Bs[buf][ldsoff]);
      if constexpr (BN == 128)
        gload16(Bg + (size_t)64 * K + k0, &Bs[buf][2048 + ldsoff]);
    } else {
      gload16(Ag + k0,                  &As[buf][ldsoff]);
      gload16(Ag + (size_t)32 * K + k0, &As[buf][2048 + ldsoff]);
      gload16(Ag + (size_t)64 * K + k0, &As[buf][4096 + ldsoff]);
      gload16(Ag + (size_t)96 * K + k0, &As[buf][6144 + ldsoff]);
      gload16(Bg + k0,                  &Bs[buf][ldsoff]);
      gload16(Bg + (size_t)32 * K + k0, &Bs[buf][2048 + ldsoff]);
      if constexpr (BN == 128) {
        gload16(Bg + (size_t)64 * K + k0, &Bs[buf][4096 + ldsoff]);
        gload16(Bg + (size_t)96 * K + k0, &Bs[buf][6144 + ldsoff]);
      }
    }
  };

  const int rsw32 = (((fr & 3) ^ ((fr >> 2) & 3)) * 8);  // BK=32 read swizzle

  for (int i = 0; i < PIPE - 1 && i < nt; ++i) STAGE(i, i * BK);
  int cur = 0;
  for (int kt = 0; kt < nt; ++kt) {
    if constexpr (WV == 3)
      asm volatile("s_waitcnt vmcnt(3)\n\ts_barrier" ::: "memory");
    else if constexpr (WV == 4)
      asm volatile("s_waitcnt vmcnt(4)\n\ts_barrier" ::: "memory");
    else if constexpr (WV == 6)
      asm volatile("s_waitcnt vmcnt(6)\n\ts_barrier" ::: "memory");
    else if constexpr (WV == 8)
      asm volatile("s_waitcnt vmcnt(8)\n\ts_barrier" ::: "memory");
    else if constexpr (WV == 12)
      asm volatile("s_waitcnt vmcnt(12)\n\ts_barrier" ::: "memory");
    else
      asm volatile("s_waitcnt vmcnt(0)\n\ts_barrier" ::: "memory");
    int nx = cur + PIPE - 1; if (nx >= PIPE) nx -= PIPE;
    if (kt + PIPE - 1 < nt) STAGE(nx, (kt + PIPE - 1) * BK);

    if constexpr (BK == 32) {
      f16x8 af[4], bf[NB];
#pragma unroll
      for (int m = 0; m < 4; ++m)
        af[m] = *(const f16x8*)&As[cur][(wr * 64 + m * 16 + fr) * 32 + ((fq * 8) ^ rsw32)];
#pragma unroll
      for (int n = 0; n < NB; ++n)
        bf[n] = *(const f16x8*)&Bs[cur][(wc * (BN / 2) + n * 16 + fr) * 32 + ((fq * 8) ^ rsw32)];
#pragma unroll
      for (int m = 0; m < 4; ++m)
#pragma unroll
        for (int n = 0; n < NB; ++n)
          acc[m][n] = __builtin_amdgcn_mfma_f32_16x16x32_f16(af[m], bf[n], acc[m][n], 0, 0, 0);
    } else {
      f16x8 af[4][KB], bf[NB][KB];
#pragma unroll
      for (int m = 0; m < 4; ++m) {
        const int ra = wr * 64 + m * 16 + fr;
#pragma unroll
        for (int kk = 0; kk < KB; ++kk)
          af[m][kk] = *(const f16x8*)&As[cur][ra * 64 + (((kk * 4 + fq) ^ (ra & 7)) * 8)];
      }
#pragma unroll
      for (int n = 0; n < NB; ++n) {
        const int rb = wc * (BN / 2) + n * 16 + fr;
#pragma unroll
        for (int kk = 0; kk < KB; ++kk)
          bf[n][kk] = *(const f16x8*)&Bs[cur][rb * 64 + (((kk * 4 + fq) ^ (rb & 7)) * 8)];
      }
#pragma unroll
      for (int kk = 0; kk < KB; ++kk)
#pragma unroll
        for (int m = 0; m < 4; ++m)
#pragma unroll
          for (int n = 0; n < NB; ++n)
            acc[m][n] = __builtin_amdgcn_mfma_f32_16x16x32_f16(af[m][kk], bf[n][kk], acc[m][n], 0, 0, 0);
    }
    ++cur; if (cur == PIPE) cur = 0;
  }

#pragma unroll
  for (int m = 0; m < 4; ++m) {
#pragma unroll
    for (int n = 0; n < NB; ++n) {
      const int col = bcol + wc * (BN / 2) + n * 16 + fr;
      const int row0 = brow + wr * 64 + m * 16 + fq * 4;
      const float bv = bias ? bias[col] : 0.f;
#pragma unroll
      for (int r = 0; r < 4; ++r) {
        const int row = row0 + r;
        if (row >= M) continue;
        float v = acc[m][n][r] + bv;
        if (do_gelu) {
          // gelu_tanh(u) == u * sigmoid(2c(u+0.044715u^3)); sigmoid via exp2
          float u = v;
          float z = u + 0.044715f * u * u * u;
          v = u / (1.f + exp2f(-2.3022083f * z));
        }
        if (Xres) {
          const float g = gate ? gate[(size_t)(row >> 10) * (6 * D_MODEL) + col] : 1.0f;
          v = Xres[(size_t)row * N + col] + g * v;
          Xres[(size_t)row * N + col] = v;
        }
        if (outb) outb[(size_t)row * N + col] = (f16)v;
        if (outf) outf[(size_t)row * N + col] = v;
      }
    }
  }
}

// ---------------------------------------------------------------------------
// MFMA flash self-attention over qkv buffer [B*N, 3D] (col = which*1024+h*64+d).
// grid (N/64, H, B), block 256 = 4 waves; wave w owns q-rows qt*64+w*16..+16.
__global__ __launch_bounds__(256) void sa_attn_kernel(
    const f16* __restrict__ qkv, f16* __restrict__ out)
{
  const int qt = blockIdx.x, h = blockIdx.y, b = blockIdx.z;
  __shared__ f16 Kl[64][72];      // [s][d]
  __shared__ f16 Vt[64][72];      // [d][s] transposed
  __shared__ f16 Pl[4][16][72];   // per-wave P strip [q_local][s]
  const int t = threadIdx.x;
  const int lane = t & 63, w = t >> 6;
  const int fr = lane & 15, fq = lane >> 4;
  const size_t base = (size_t)b * SEQ_N * 3072 + h * 64;

  const int qrow = qt * 64 + w * 16 + fr;
  f16x8 qa[2];
#pragma unroll
  for (int kk = 0; kk < 2; ++kk) {
    qa[kk] = *(const f16x8*)&qkv[base + (size_t)qrow * 3072 + kk * 32 + fq * 8];
#pragma unroll
    for (int j = 0; j < 8; ++j)
      qa[kk][j] = (f16)((float)qa[kk][j] * LOG2E_SCALE);
  }

  f32x4 o_acc[4] = {};
  float m_run[4], l_run[4];
#pragma unroll
  for (int r = 0; r < 4; ++r) { m_run[r] = -1e30f; l_run[r] = 0.f; }

  const int ksr = t >> 2, ksc = (t & 3) * 8;   // K: 64 rows x 4 chunks, vector
  const int vs = t & 63, vd = (t >> 6) * 16;   // V: per-wave one d-group, all s
  f16x8 kreg0, kreg1, vreg0, vreg1;

  auto LOADKV = [&](int s0) {
    kreg0 = *(const f16x8*)&qkv[base + (size_t)(s0 + ksr) * 3072 + 1024 + ksc];
    kreg1 = *(const f16x8*)&qkv[base + (size_t)(s0 + ksr) * 3072 + 1024 + ksc + 32];
    vreg0 = *(const f16x8*)&qkv[base + (size_t)(s0 + vs) * 3072 + 2048 + vd];
    vreg1 = *(const f16x8*)&qkv[base + (size_t)(s0 + vs) * 3072 + 2048 + vd + 8];
  };

  LOADKV(0);
  for (int s0 = 0; s0 < SEQ_N; s0 += 64) {
    __syncthreads();
    *(f16x8*)&Kl[ksr][ksc]      = kreg0;
    *(f16x8*)&Kl[ksr][ksc + 32] = kreg1;
#pragma unroll
    for (int j = 0; j < 8; ++j) {
      Vt[vd + j][vs]     = vreg0[j];
      Vt[vd + 8 + j][vs] = vreg1[j];
    }
    __syncthreads();
    if (s0 + 64 < SEQ_N) LOADKV(s0 + 64);

    f32x4 sf[4] = {};
#pragma unroll
    for (int kk = 0; kk < 2; ++kk) {
#pragma unroll
      for (int n = 0; n < 4; ++n) {
        f16x8 kb = *(const f16x8*)&Kl[n * 16 + fr][kk * 32 + fq * 8];
        sf[n] = __builtin_amdgcn_mfma_f32_16x16x32_f16(qa[kk], kb, sf[n], 0, 0, 0);
      }
    }

#pragma unroll
    for (int r = 0; r < 4; ++r) {
      float v = fmaxf(fmaxf(sf[0][r], sf[1][r]), fmaxf(sf[2][r], sf[3][r]));
#pragma unroll
      for (int o = 1; o < 16; o <<= 1) v = fmaxf(v, __shfl_xor(v, o));
      const float mn = fmaxf(m_run[r], v);
      const float f = exp2f(m_run[r] - mn);
      m_run[r] = mn;
#pragma unroll
      for (int n = 0; n < 4; ++n) o_acc[n][r] *= f;
      float rs = 0.f;
#pragma unroll
      for (int n = 0; n < 4; ++n) {
        float p = exp2f(sf[n][r] - mn);
        sf[n][r] = p;
        rs += p;
      }
      l_run[r] = l_run[r] * f + rs;
    }

#pragma unroll
    for (int n = 0; n < 4; ++n)
#pragma unroll
      for (int r = 0; r < 4; ++r)
        Pl[w][fq * 4 + r][n * 16 + fr] = (f16)sf[n][r];

#pragma unroll
    for (int kk = 0; kk < 2; ++kk) {
      f16x8 pa = *(const f16x8*)&Pl[w][fr][kk * 32 + fq * 8];
#pragma unroll
      for (int n = 0; n < 4; ++n) {
        f16x8 vb = *(const f16x8*)&Vt[n * 16 + fr][kk * 32 + fq * 8];
        o_acc[n] = __builtin_amdgcn_mfma_f32_16x16x32_f16(pa, vb, o_acc[n], 0, 0, 0);
      }
    }
  }

  const size_t orow = (size_t)(b * SEQ_N + qt * 64 + w * 16) * D_MODEL + h * 64;
#pragma unroll
  for (int r = 0; r < 4; ++r) {
    float l = l_run[r];
#pragma unroll
    for (int o = 1; o < 16; o <<= 1) l += __shfl_xor(l, o);
    const float inv = 1.f / l;
#pragma unroll
    for (int n = 0; n < 4; ++n)
      out[orow + (size_t)(fq * 4 + r) * D_MODEL + n * 16 + fr] = (f16)(o_acc[n][r] * inv);
  }
}

// ---------------------------------------------------------------------------
// Cross-attention: q [B*N, D], kv [B*S, 2D] (col = which*1024 + h*64 + d).
__global__ __launch_bounds__(256) void ca_attn_kernel(
    const f16* __restrict__ qb, const f16* __restrict__ kvb,
    f16* __restrict__ out)
{
  const int qt = blockIdx.x, h = blockIdx.y, b = blockIdx.z;
  __shared__ float qs[16][68];
  __shared__ float sc[16][80];
  __shared__ f16 kt[77][72];
  __shared__ f16 vt[77][72];
  const int t = threadIdx.x;
  for (int i = t; i < 16 * 64; i += 256) {
    int q = i >> 6, d = i & 63;
    qs[q][d] = (float)qb[(size_t)(b * SEQ_N + qt * 16 + q) * D_MODEL + h * 64 + d];
  }
  for (int i = t; i < SEQ_S * 8; i += 256) {
    int r = i >> 3, c = (i & 7) * 8;
    *(f16x8*)&kt[r][c] = *(const f16x8*)&kvb[(size_t)(b * SEQ_S + r) * 2048 + h * 64 + c];
    *(f16x8*)&vt[r][c] = *(const f16x8*)&kvb[(size_t)(b * SEQ_S + r) * 2048 + 1024 + h * 64 + c];
  }
  __syncthreads();
  for (int idx = t; idx < 16 * 80; idx += 256) {
    int q = idx / 80, s = idx % 80;
    float a = -1e30f;
    if (s < SEQ_S) {
      a = 0.f;
      for (int d = 0; d < 64; ++d) a += qs[q][d] * (float)kt[s][d];
      a *= LOG2E_SCALE;
    }
    sc[q][s] = a;
  }
  __syncthreads();
  const int lane = t & 63, w = t >> 6;
  for (int q = w; q < 16; q += 4) {
    float m = -1e30f;
    for (int j = lane; j < 80; j += 64) m = fmaxf(m, sc[q][j]);
    for (int o = 32; o; o >>= 1) m = fmaxf(m, __shfl_xor(m, o));
    float sum = 0.f;
    for (int j = lane; j < 80; j += 64) {
      float e = (j < SEQ_S) ? exp2f(sc[q][j] - m) : 0.f;
      sc[q][j] = e; sum += e;
    }
    for (int o = 32; o; o >>= 1) sum += __shfl_xor(sum, o);
    float inv = 1.f / sum;
    for (int j = lane; j < 80; j += 64) sc[q][j] *= inv;
  }
  __syncthreads();
  const int q = t >> 4, d0 = (t & 15) * 4;
  float a0 = 0, a1 = 0, a2 = 0, a3 = 0;
  for (int s = 0; s < SEQ_S; ++s) {
    float p = sc[q][s];
    a0 += p * (float)vt[s][d0];
    a1 += p * (float)vt[s][d0 + 1];
    a2 += p * (float)vt[s][d0 + 2];
    a3 += p * (float)vt[s][d0 + 3];
  }
  size_t orow = (size_t)(b * SEQ_N + qt * 16 + q) * D_MODEL + h * 64;
  out[orow + d0] = (f16)a0;
  out[orow + d0 + 1] = (f16)a1;
  out[orow + d0 + 2] = (f16)a2;
  out[orow + d0 + 3] = (f16)a3;
}

// ---------------------------------------------------------------------------
extern "C" void kernel_launch(void* const* d_in, const int* in_sizes, int n_in,
                              void* d_out, int out_size, void* d_ws, size_t ws_size,
                              hipStream_t stream)
{
  const float* x       = (const float*)d_in[0];
  const float* t_emb   = (const float*)d_in[1];
  const float* ctx     = (const float*)d_in[2];
  const float* adaln_w = (const float*)d_in[3];
  const float* adaln_b = (const float*)d_in[4];
  const float* qkv_w   = (const float*)d_in[5];
  const float* qkv_b   = (const float*)d_in[6];
  const float* sa_pw   = (const float*)d_in[7];
  const float* sa_pb   = (const float*)d_in[8];
  const float* q_w     = (const float*)d_in[9];
  const float* q_b     = (const float*)d_in[10];
  const float* kv_w    = (const float*)d_in[11];
  const float* kv_b    = (const float*)d_in[12];
  const float* ca_pw   = (const float*)d_in[13];
  const float* ca_pb   = (const float*)d_in[14];
  const float* fc1_w   = (const float*)d_in[15];
  const float* fc1_b   = (const float*)d_in[16];
  const float* fc2_w   = (const float*)d_in[17];
  const float* fc2_b   = (const float*)d_in[18];
  float* out = (float*)d_out;

  // ---- workspace layout (all regions DISJOINT) ----
  char* ws = (char*)d_ws;
  float* mod    = (float*)(ws + 0);            //    98,304 B  [B,6D] f32
  float* X      = (float*)(ws + 98304);        // 16,777,216 B residual f32
  f16*   bufA   = (f16*)(ws + 16875520);       //  8,388,608 B (xm / xn / xm_ff)
  f16*   bufB   = (f16*)(ws + 25264128);       // 25,165,824 B (qkv / q / h)
  f16*   bufC   = (f16*)(ws + 50429952);       //  8,388,608 B (attn out)
  f16*   bufKV  = (f16*)(ws + 58818560);       //  1,261,568 B (kv, 308x2048)
  f16*   ctxh   = (f16*)(ws + 60080128);       //    786,432 B (ctx f16, PADDED to 384 rows)
  f16*   qkv_wt = (f16*)(ws + 60866560);       //  6,291,456 B [3072][1024]
  f16*   kv_wt  = (f16*)(ws + 67158016);       //  4,194,304 B [2048][1024]
  f16*   sa_pwt = (f16*)(ws + 71352320);       //  2,097,152 B [1024][1024]
  f16*   q_wt   = (f16*)(ws + 73449472);       //  2,097,152 B
  f16*   ca_pwt = (f16*)(ws + 75546624);       //  2,097,152 B
  f16*   fc1_wt = (f16*)(ws + 77643776);       //  8,388,608 B [4096][1024]
  f16*   fc2_wt = (f16*)(ws + 86032384);       //  8,388,608 B [1024][4096]
  f16*   bufQ   = bufB;                         // total 94,420,992 B

  const dim3 blk(256);
  const int TOK = BATCH * SEQ_N;  // 4096

  // ---- fused weight transposes (f32 [K,N] -> f16 [N,K]) ----
  WtAll wa;
  wa.src[0] = qkv_w; wa.dst[0] = qkv_wt;
  wa.src[1] = kv_w;  wa.dst[1] = kv_wt;
  wa.src[2] = sa_pw; wa.dst[2] = sa_pwt;
  wa.src[3] = q_w;   wa.dst[3] = q_wt;
  wa.src[4] = ca_pw; wa.dst[4] = ca_pwt;
  wa.src[5] = fc1_w; wa.dst[5] = fc1_wt;
  wa.src[6] = fc2_w; wa.dst[6] = fc2_wt;
  wt_all_kernel<<<dim3(4096), blk, 0, stream>>>(wa);

  // AdaLN modulation params
  mod_kernel<<<dim3(24, BATCH), blk, 0, stream>>>(t_emb, adaln_w, adaln_b, mod);
  // X = x (f32) ; ctx -> f16   (fused)
  initcvt_kernel<<<dim3(16384 + (CTX_ELE + 255) / 256), blk, 0, stream>>>(
      x, X, ctx, ctxh);

  // --- self-attention branch ---  offsets: sh_sa=0, sc_sa=1024, g_sa=2048
  lnmod_kernel<<<TOK, blk, 0, stream>>>(X, mod, 1024, 0, bufA);
  // QKV: reverted to the proven wide-N config (round 12: 85.5 us, FETCH 70 MB)
  gemm_kernel<128, 32, 3><<<dim3(3072 / 128, TOK / 128), blk, 0, stream>>>(
      bufA, qkv_wt, qkv_b, nullptr, nullptr, bufB, nullptr, TOK, 3072, 1024, 0);
  // kv gemm (M=308; A buffer padded to 384 readable rows)
  gemm_kernel<64, 64, 3><<<dim3(2048 / 64, 3), blk, 0, stream>>>(
      ctxh, kv_wt, kv_b, nullptr, nullptr, bufKV, nullptr, BATCH * SEQ_S, 2048, 1024, 0);
  sa_attn_kernel<<<dim3(SEQ_N / 64, NHEAD, BATCH), blk, 0, stream>>>(bufB, bufC);
  gemm_kernel<64, 64, 3><<<dim3(1024 / 64, TOK / 128), blk, 0, stream>>>(
      bufC, sa_pwt, sa_pb, X, mod + 2048, nullptr, nullptr, TOK, 1024, 1024, 0);

  // --- cross-attention branch ---
  lnmod_kernel<<<TOK, blk, 0, stream>>>(X, nullptr, 0, 0, bufA);
  gemm_kernel<64, 64, 3><<<dim3(1024 / 64, TOK / 128), blk, 0, stream>>>(
      bufA, q_wt, q_b, nullptr, nullptr, bufQ, nullptr, TOK, 1024, 1024, 0);
  ca_attn_kernel<<<dim3(SEQ_N / 16, NHEAD, BATCH), blk, 0, stream>>>(bufQ, bufKV, bufC);
  gemm_kernel<64, 64, 3><<<dim3(1024 / 64, TOK / 128), blk, 0, stream>>>(
      bufC, ca_pwt, ca_pb, X, nullptr, nullptr, nullptr, TOK, 1024, 1024, 0);

  // --- MLP branch ---  offsets: sh_ff=3072, sc_ff=4096, g_ff=5120
  lnmod_kernel<<<TOK, blk, 0, stream>>>(X, mod, 4096, 3072, bufA);
  // FC1: EXPERIMENT <128,64,2> — same 128x128 reuse as <128,32,3>, half the
  // barriers; within-profile A/B against QKV (same M,K, near-same N).
  gemm_kernel<128, 64, 2><<<dim3(MLP_DIM / 128, TOK / 128), blk, 0, stream>>>(
      bufA, fc1_wt, fc1_b, nullptr, nullptr, bufB, nullptr, TOK, MLP_DIM, 1024, 1);
  gemm_kernel<64, 64, 3><<<dim3(1024 / 64, TOK / 128), blk, 0, stream>>>(
      bufB, fc2_wt, fc2_b, X, mod + 5120, nullptr, out, TOK, 1024, MLP_DIM, 0);
}